// Round 16
// baseline (3016.634 us; speedup 1.0000x reference)
//
#include <hip/hip_runtime.h>
#include <hip/hip_bf16.h>
#include <cstdint>

// Problem constants (match reference)
#define M_TOK 8192
#define K_IN  4096
#define N_OUT 11008
#define NP8   (N_OUT / 8)
#define GS    128

// DTYPE CONTRACT (verified round 4): x/scales/bias/out are float32 on device;
// qweight/qzeros are int32.

typedef __attribute__((ext_vector_type(8))) short  s16x8;
typedef __attribute__((ext_vector_type(8))) __bf16 bf16x8;
typedef __attribute__((ext_vector_type(4))) float  f32x4;

// ---------------------------------------------------------------------------
__global__ __launch_bounds__(256) void convert_x_kernel(
    const float* __restrict__ in, unsigned short* __restrict__ outp, long n8)
{
    long i = (long)blockIdx.x * blockDim.x + threadIdx.x;
    const long stride = (long)gridDim.x * blockDim.x;
    for (; i < n8; i += stride) {
        const float4 a = ((const float4*)in)[2 * i];
        const float4 b = ((const float4*)in)[2 * i + 1];
        bf16x8 h;
        h[0] = (__bf16)a.x; h[1] = (__bf16)a.y; h[2] = (__bf16)a.z; h[3] = (__bf16)a.w;
        h[4] = (__bf16)b.x; h[5] = (__bf16)b.y; h[6] = (__bf16)b.z; h[7] = (__bf16)b.w;
        ((int4*)outp)[i] = __builtin_bit_cast(int4, h);
    }
}

// ---------------------------------------------------------------------------
__global__ __launch_bounds__(256) void dequant_kernel(
    const unsigned int* __restrict__ qw,
    const unsigned int* __restrict__ qz,
    const float*        __restrict__ sc,
    unsigned short*     __restrict__ wt,
    int n_base)
{
    const int tid = threadIdx.x;
    const int k8  = tid & 15;
    const int n8  = tid >> 4;
    const int g   = blockIdx.x;
    const int k0  = g * GS + k8 * 8;
    const int ncl = blockIdx.y * 128 + n8 * 8;
    const int ng  = n_base + ncl;
    const int j8  = ng >> 3;

    const unsigned int z = qz[(size_t)g * NP8 + j8];

    float s[8];
    *(float4*)&s[0] = *(const float4*)&sc[(size_t)g * N_OUT + ng];
    *(float4*)&s[4] = *(const float4*)&sc[(size_t)g * N_OUT + ng + 4];

    unsigned int q[8];
#pragma unroll
    for (int i = 0; i < 8; i++) q[i] = qw[(size_t)(k0 + i) * NP8 + j8];

#pragma unroll
    for (int t = 0; t < 8; t++) {
        const float sf  = s[t];
        const float nzs = -(float)((z >> (4 * t)) & 0xFu) * sf;
        bf16x8 h;
#pragma unroll
        for (int i = 0; i < 8; i++) {
            const float nib = (float)((q[i] >> (4 * t)) & 0xFu);
            h[i] = (__bf16)fmaf(nib, sf, nzs);
        }
        *(int4*)&wt[(size_t)(ncl + t) * K_IN + k0] = __builtin_bit_cast(int4, h);
    }
}

// ---------------------------------------------------------------------------
// r16: m201-style 8-phase 256x256 GEMM. BK=64, buf0=even K-step, buf1=odd.
// 8 waves (2M x 4N), wave tile 128x64. Frag reads decoupled from MFMA by
// 4-6 phases; stages spread 1 half-tile/phase; gates: lgkm-barrier at ph0/ph4
// (LDS reuse), lgkm+vmcnt(4)-barrier at ph2/ph6 (staged data resident,
// 4 newest loads stay in flight). T2 swizzle both sides; T5 setprio.
// ---------------------------------------------------------------------------
#define GLOAD16(gp, lp)                                                        \
    __builtin_amdgcn_global_load_lds(                                          \
        (const __attribute__((address_space(1))) void*)(gp),                   \
        (__attribute__((address_space(3))) void*)(lp), 16, 0, 0)

__global__ __launch_bounds__(512, 1) void gemm_8phase_kernel(
    const unsigned short* __restrict__ A,     // xb [M][K] bf16
    const unsigned short* __restrict__ Bt,    // wt chunk [nc][K] bf16
    const float*          __restrict__ bias,  // [N] f32
    float*                __restrict__ C,     // [M][N] f32
    int n_base)
{
    // [buf][row-half][row*64+elem] ; 2*2*16KB per matrix = 128 KB total
    __shared__ __align__(16) unsigned short Asb[2][2][128 * 64];
    __shared__ __align__(16) unsigned short Bsb[2][2][128 * 64];

    const int tid = threadIdx.x;
    const int l   = tid & 63;
    const int w   = tid >> 6;       // wave 0..7
    const int wm  = w >> 2;         // 0..1: rows wm*128..+127
    const int wn  = w & 3;          // 0..3: cols wn*64..+63

    // --- bijective XCD swizzle (m204)
    const int nwg = gridDim.x;      // 32 * 43 = 1376
    const int q8  = nwg >> 3, r8 = nwg & 7;
    const int xcd = blockIdx.x & 7, idx = blockIdx.x >> 3;
    const int swz = ((xcd < r8) ? xcd * (q8 + 1) : r8 * (q8 + 1) + (xcd - r8) * q8) + idx;
    const int mtile = swz & 31;
    const int ntile = swz >> 5;

    const size_t blockM = (size_t)mtile * 256;
    const int    colc   = ntile * 256;

    const unsigned short* Ag = A  + blockM * K_IN;
    const unsigned short* Bg = Bt + (size_t)colc * K_IN;

    // --- staging roles: 8 threads/row (16B chunks), 64 rows per pass
    const int row_in = tid >> 3;             // 0..63
    const int cch    = tid & 7;              // physical chunk
    const int kcs    = cch ^ (row_in & 7);   // logical chunk (inverse swizzle)

#define STG(GP, ARR, b_, h_, step_)                                            \
    do {                                                                       \
        _Pragma("unroll")                                                      \
        for (int q = 0; q < 2; q++)                                            \
            GLOAD16(GP + (size_t)((h_) * 128 + q * 64 + row_in) * K_IN         \
                       + (size_t)(step_) * 64 + kcs * 8,                       \
                    &ARR[b_][h_][(q * 64 + w * 8) * 64]);                      \
    } while (0)

    // --- compute roles
    const int lrow = l & 15;
    const int lk   = l >> 4;                 // 0..3
    int aro[8], bro[4], ach[2];
#pragma unroll
    for (int mi = 0; mi < 8; mi++) aro[mi] = (mi * 16 + lrow) * 64;
#pragma unroll
    for (int ni = 0; ni < 4; ni++) bro[ni] = ((wn & 1) * 64 + ni * 16 + lrow) * 64;
#pragma unroll
    for (int kk = 0; kk < 2; kk++) ach[kk] = ((kk * 4 + lk) ^ (lrow & 7)) * 8;

    const unsigned short* Ab[2] = { &Asb[0][wm][0],      &Asb[1][wm][0] };
    const unsigned short* Bb[2] = { &Bsb[0][wn >> 1][0], &Bsb[1][wn >> 1][0] };

    s16x8 A0[8][2], B0[4][2], A1[8][2], B1[4][2];
    f32x4 acc[8][4];
#pragma unroll
    for (int i = 0; i < 8; i++)
#pragma unroll
        for (int j = 0; j < 4; j++) acc[i][j] = (f32x4){0.f, 0.f, 0.f, 0.f};

#define READ_A(dst, base, lo, hi)                                              \
    do {                                                                       \
        _Pragma("unroll")                                                      \
        for (int mi = (lo); mi <= (hi); mi++)                                  \
            _Pragma("unroll")                                                  \
            for (int kk = 0; kk < 2; kk++)                                     \
                dst[mi][kk] = *(const s16x8*)&base[aro[mi] + ach[kk]];         \
    } while (0)

#define READ_B(dst, base)                                                      \
    do {                                                                       \
        _Pragma("unroll")                                                      \
        for (int ni = 0; ni < 4; ni++)                                         \
            _Pragma("unroll")                                                  \
            for (int kk = 0; kk < 2; kk++)                                     \
                dst[ni][kk] = *(const s16x8*)&base[bro[ni] + ach[kk]];         \
    } while (0)

#define MFMA_CL(Aset, Bset, c_)                                                \
    do {                                                                       \
        __builtin_amdgcn_s_setprio(1);                                         \
        _Pragma("unroll")                                                      \
        for (int kk = 0; kk < 2; kk++)                                         \
            _Pragma("unroll")                                                  \
            for (int ni = 0; ni < 4; ni++)                                     \
                _Pragma("unroll")                                              \
                for (int dm = 0; dm < 2; dm++)                                 \
                    acc[2 * (c_) + dm][ni] =                                   \
                        __builtin_amdgcn_mfma_f32_16x16x32_bf16(               \
                            __builtin_bit_cast(bf16x8, Aset[2 * (c_) + dm][kk]),\
                            __builtin_bit_cast(bf16x8, Bset[ni][kk]),          \
                            acc[2 * (c_) + dm][ni], 0, 0, 0);                  \
        __builtin_amdgcn_s_setprio(0);                                         \
    } while (0)

#define GATE_L()                                                               \
    do { asm volatile("s_waitcnt lgkmcnt(0)" ::: "memory");                    \
         __builtin_amdgcn_s_barrier();                                         \
         __builtin_amdgcn_sched_barrier(0); } while (0)

#define GATE_V()                                                               \
    do { asm volatile("s_waitcnt lgkmcnt(0)" ::: "memory");                    \
         asm volatile("s_waitcnt vmcnt(4)" ::: "memory");                      \
         __builtin_amdgcn_s_barrier();                                         \
         __builtin_amdgcn_sched_barrier(0); } while (0)

    const int NT = K_IN / 64;   // 64 K-steps

    // Prologue: stage step0 -> buf0, step1 -> buf1 (16 loads), then read step0.
    STG(Ag, Asb, 0, 0, 0); STG(Ag, Asb, 0, 1, 0);
    STG(Bg, Bsb, 0, 0, 0); STG(Bg, Bsb, 0, 1, 0);
    STG(Ag, Asb, 1, 0, 1); STG(Ag, Asb, 1, 1, 1);
    STG(Bg, Bsb, 1, 0, 1); STG(Bg, Bsb, 1, 1, 1);
    asm volatile("s_waitcnt vmcnt(8)" ::: "memory");   // buf0's 8 loads done
    __builtin_amdgcn_s_barrier();
    __builtin_amdgcn_sched_barrier(0);
    READ_A(A0, Ab[0], 0, 7);
    READ_B(B0, Bb[0]);

    for (int i = 0; i < NT / 2; ++i) {
        const int s2 = 2 * i + 2;   // -> buf0
        const int s3 = 2 * i + 3;   // -> buf1
        // ph0: gate(L); stage A0h0<-s2; MFMA cur c0
        GATE_L();
        if (s2 < NT) STG(Ag, Asb, 0, 0, s2);
        MFMA_CL(A0, B0, 0);
        // ph1: stage A0h1; MFMA cur c1
        if (s2 < NT) STG(Ag, Asb, 0, 1, s2);
        MFMA_CL(A0, B0, 1);
        // ph2: gate(V); read s1 (A mi0-3 + B) from buf1; stage B0h0; MFMA cur c2
        GATE_V();
        READ_A(A1, Ab[1], 0, 3);
        READ_B(B1, Bb[1]);
        if (s2 < NT) STG(Bg, Bsb, 0, 0, s2);
        MFMA_CL(A0, B0, 2);
        // ph3: read s1 A mi4-7; stage B0h1; MFMA cur c3
        READ_A(A1, Ab[1], 4, 7);
        if (s2 < NT) STG(Bg, Bsb, 0, 1, s2);
        MFMA_CL(A0, B0, 3);
        // ph4: gate(L); stage A1h0<-s3; MFMA nxt c0
        GATE_L();
        if (s3 < NT) STG(Ag, Asb, 1, 0, s3);
        MFMA_CL(A1, B1, 0);
        // ph5: stage A1h1; MFMA nxt c1
        if (s3 < NT) STG(Ag, Asb, 1, 1, s3);
        MFMA_CL(A1, B1, 1);
        // ph6: gate(V); read s2 (A mi0-3 + B) from buf0; stage B1h0; MFMA nxt c2
        GATE_V();
        if (s2 < NT) { READ_A(A0, Ab[0], 0, 3); READ_B(B0, Bb[0]); }
        if (s3 < NT) STG(Bg, Bsb, 1, 0, s3);
        MFMA_CL(A1, B1, 2);
        // ph7: read s2 A mi4-7; stage B1h1; MFMA nxt c3
        if (s2 < NT) READ_A(A0, Ab[0], 4, 7);
        if (s3 < NT) STG(Bg, Bsb, 1, 1, s3);
        MFMA_CL(A1, B1, 3);
    }
#undef STG
#undef READ_A
#undef READ_B
#undef MFMA_CL
#undef GATE_L
#undef GATE_V

    // Epilogue: C/D layout col = lane&15, row = (lane>>4)*4 + reg (m89)
#pragma unroll
    for (int ni = 0; ni < 4; ++ni) {
        const int ng = n_base + colc + wn * 64 + ni * 16 + lrow;
        const float bv = bias[ng];
#pragma unroll
        for (int mi = 0; mi < 8; ++mi) {
            f32x4 v = acc[mi][ni];
#pragma unroll
            for (int r = 0; r < 4; r++) {
                const size_t grow = blockM + wm * 128 + mi * 16 + lk * 4 + r;
                C[grow * N_OUT + ng] = v[r] + bv;
            }
        }
    }
}

// ---------------------------------------------------------------------------
// Fallback: fully fused kernel (passed round 4, verbatim).
// ---------------------------------------------------------------------------
__global__ __launch_bounds__(256) void fused_w4a16_kernel(
    const float*        __restrict__ A,
    const unsigned int* __restrict__ qw,
    const unsigned int* __restrict__ qz,
    const float*        __restrict__ sc,
    const float*        __restrict__ bias,
    float*              __restrict__ C)
{
    __shared__ __align__(16) unsigned short As[128 * 64];
    __shared__ __align__(16) unsigned short Bs[128 * 64];

    const int tid = threadIdx.x;
    const int l   = tid & 63;
    const int w   = tid >> 6;
    const int wm  = w >> 1;
    const int wn  = w & 1;
    const size_t blockM = (size_t)blockIdx.x * 128;
    const int    colN   = blockIdx.y * 128;

    const float* Ag = A + blockM * K_IN;

    const int r_in = l >> 3;
    const int cch  = l & 7;
    int    aw_off[4];
    size_t ag_off[4];
#pragma unroll
    for (int qq = 0; qq < 4; qq++) {
        const int row = w * 32 + qq * 8 + r_in;
        aw_off[qq] = row * 64 + ((cch ^ r_in) * 8);
        ag_off[qq] = (size_t)row * K_IN + cch * 8;
    }

    const int kc = tid & 7;
    int ngl[4], j8[4], shn[4], bs_off[4];
#pragma unroll
    for (int p = 0; p < 4; p++) {
        const int nl = p * 32 + (tid >> 3);
        const int ng = colN + nl;
        ngl[p]    = ng;
        j8[p]     = ng >> 3;
        shn[p]    = 4 * (ng & 7);
        bs_off[p] = nl * 64 + ((kc ^ (nl & 7)) * 8);
    }

    f32x4 acc[4][4];
#pragma unroll
    for (int i = 0; i < 4; i++)
#pragma unroll
        for (int j = 0; j < 4; j++) acc[i][j] = (f32x4){0.f, 0.f, 0.f, 0.f};

    const int lrow = l & 15;
    const int lk   = l >> 4;
    const int NT   = K_IN / 64;

    for (int kt = 0; kt < NT; ++kt) {
        const int K0 = kt * 64;
        const int g  = K0 >> 7;

        float4 fa[4][2];
#pragma unroll
        for (int qq = 0; qq < 4; qq++) {
            fa[qq][0] = *(const float4*)(Ag + ag_off[qq] + K0);
            fa[qq][1] = *(const float4*)(Ag + ag_off[qq] + K0 + 4);
        }

        unsigned int q[4][8];
        float sf[4], nzs[4];
#pragma unroll
        for (int p = 0; p < 4; p++) {
            const unsigned int* qp = qw + (size_t)(K0 + kc * 8) * NP8 + j8[p];
#pragma unroll
            for (int i = 0; i < 8; i++) q[p][i] = qp[(size_t)i * NP8];
            const float zf = (float)((qz[(size_t)g * NP8 + j8[p]] >> shn[p]) & 0xFu);
            sf[p]  = sc[(size_t)g * N_OUT + ngl[p]];
            nzs[p] = -zf * sf[p];
        }

        __syncthreads();

#pragma unroll
        for (int qq = 0; qq < 4; qq++) {
            bf16x8 h;
#pragma unroll
            for (int i = 0; i < 4; i++) {
                h[i]     = (__bf16)(((const float*)&fa[qq][0])[i]);
                h[i + 4] = (__bf16)(((const float*)&fa[qq][1])[i]);
            }
            *(int4*)&As[aw_off[qq]] = __builtin_bit_cast(int4, h);
        }
#pragma unroll
        for (int p = 0; p < 4; p++) {
            bf16x8 h;
#pragma unroll
            for (int i = 0; i < 8; i++) {
                const float nib = (float)((q[p][i] >> shn[p]) & 0xFu);
                h[i] = (__bf16)fmaf(nib, sf[p], nzs[p]);
            }
            *(int4*)&Bs[bs_off[p]] = __builtin_bit_cast(int4, h);
        }

        __syncthreads();

#pragma unroll
        for (int ks = 0; ks < 2; ++ks) {
            s16x8 a[4], b[4];
            const int kcc = ks * 4 + lk;
#pragma unroll
            for (int mi = 0; mi < 4; mi++) {
                const int row = wm * 64 + mi * 16 + lrow;
                a[mi] = *(const s16x8*)&As[row * 64 + ((kcc ^ (row & 7)) * 8)];
            }
#pragma unroll
            for (int ni = 0; ni < 4; ni++) {
                const int row = wn * 64 + ni * 16 + lrow;
                b[ni] = *(const s16x8*)&Bs[row * 64 + ((kcc ^ (row & 7)) * 8)];
            }
#pragma unroll
            for (int mi = 0; mi < 4; mi++)
#pragma unroll
                for (int ni = 0; ni < 4; ni++)
                    acc[mi][ni] = __builtin_amdgcn_mfma_f32_16x16x32_bf16(
                        __builtin_bit_cast(bf16x8, a[mi]),
                        __builtin_bit_cast(bf16x8, b[ni]),
                        acc[mi][ni], 0, 0, 0);
        }
    }

#pragma unroll
    for (int ni = 0; ni < 4; ++ni) {
        const int ng = colN + wn * 64 + ni * 16 + lrow;
        const float bv = bias[ng];
#pragma unroll
        for (int mi = 0; mi < 4; ++mi) {
            f32x4 v = acc[mi][ni];
#pragma unroll
            for (int r = 0; r < 4; r++) {
                const size_t grow = blockM + wm * 64 + mi * 16 + lk * 4 + r;
                C[grow * N_OUT + ng] = v[r] + bv;
            }
        }
    }
}

// ---------------------------------------------------------------------------
extern "C" void kernel_launch(void* const* d_in, const int* in_sizes, int n_in,
                              void* d_out, int out_size, void* d_ws, size_t ws_size,
                              hipStream_t stream)
{
    const float*        x    = (const float*)d_in[0];
    const unsigned int* qw   = (const unsigned int*)d_in[1];
    const unsigned int* qz   = (const unsigned int*)d_in[2];
    const float*        sc   = (const float*)d_in[3];
    const float*        bias = (const float*)d_in[4];
    float*              out  = (float*)d_out;

    const size_t XBF    = (size_t)M_TOK * K_IN * 2;   // 64 MiB bf16 x
    const size_t COL256 = (size_t)256 * K_IN * 2;     // 2 MiB per 256 cols W^T

    if (ws_size >= XBF + COL256) {
        // Tier A (proven firing r6-r15): convert x once, chunked dequant +
        // 8-phase 256x256 gemm.
        unsigned short* xb = (unsigned short*)d_ws;
        unsigned short* wt = (unsigned short*)((char*)d_ws + XBF);
        const long n8 = (long)M_TOK * K_IN / 8;
        convert_x_kernel<<<2048, 256, 0, stream>>>(x, xb, n8);

        size_t chunk_cols = ((ws_size - XBF) / COL256) * 256;
        if (chunk_cols > (size_t)N_OUT) chunk_cols = N_OUT;
        for (int n0 = 0; n0 < N_OUT; n0 += (int)chunk_cols) {
            int nc = N_OUT - n0;
            if (nc > (int)chunk_cols) nc = (int)chunk_cols;
            dequant_kernel<<<dim3(K_IN / GS, nc / 128), 256, 0, stream>>>(qw, qz, sc, wt, n0);
            gemm_8phase_kernel<<<32 * (nc / 256), 512, 0, stream>>>(xb, wt, bias, out, n0);
        }
    } else {
        // Fallback: fully fused (proven round 4).
        fused_w4a16_kernel<<<dim3(M_TOK / 128, N_OUT / 128), 256, 0, stream>>>(
            x, qw, qz, sc, bias, out);
    }
}

// Round 17
// 857.799 us; speedup vs baseline: 3.5167x; 3.5167x over previous
//
#include <hip/hip_runtime.h>
#include <hip/hip_bf16.h>
#include <cstdint>

// Problem constants (match reference)
#define M_TOK 8192
#define K_IN  4096
#define N_OUT 11008
#define NP8   (N_OUT / 8)
#define GS    128

// DTYPE CONTRACT (verified round 4): x/scales/bias/out are float32 on device;
// qweight/qzeros are int32.

typedef __attribute__((ext_vector_type(8))) short  s16x8;
typedef __attribute__((ext_vector_type(8))) __bf16 bf16x8;
typedef __attribute__((ext_vector_type(4))) float  f32x4;

// ---------------------------------------------------------------------------
__global__ __launch_bounds__(256) void convert_x_kernel(
    const float* __restrict__ in, unsigned short* __restrict__ outp, long n8)
{
    long i = (long)blockIdx.x * blockDim.x + threadIdx.x;
    const long stride = (long)gridDim.x * blockDim.x;
    for (; i < n8; i += stride) {
        const float4 a = ((const float4*)in)[2 * i];
        const float4 b = ((const float4*)in)[2 * i + 1];
        bf16x8 h;
        h[0] = (__bf16)a.x; h[1] = (__bf16)a.y; h[2] = (__bf16)a.z; h[3] = (__bf16)a.w;
        h[4] = (__bf16)b.x; h[5] = (__bf16)b.y; h[6] = (__bf16)b.z; h[7] = (__bf16)b.w;
        ((int4*)outp)[i] = __builtin_bit_cast(int4, h);
    }
}

// ---------------------------------------------------------------------------
__global__ __launch_bounds__(256) void dequant_kernel(
    const unsigned int* __restrict__ qw,
    const unsigned int* __restrict__ qz,
    const float*        __restrict__ sc,
    unsigned short*     __restrict__ wt,
    int n_base)
{
    const int tid = threadIdx.x;
    const int k8  = tid & 15;
    const int n8  = tid >> 4;
    const int g   = blockIdx.x;
    const int k0  = g * GS + k8 * 8;
    const int ncl = blockIdx.y * 128 + n8 * 8;
    const int ng  = n_base + ncl;
    const int j8  = ng >> 3;

    const unsigned int z = qz[(size_t)g * NP8 + j8];

    float s[8];
    *(float4*)&s[0] = *(const float4*)&sc[(size_t)g * N_OUT + ng];
    *(float4*)&s[4] = *(const float4*)&sc[(size_t)g * N_OUT + ng + 4];

    unsigned int q[8];
#pragma unroll
    for (int i = 0; i < 8; i++) q[i] = qw[(size_t)(k0 + i) * NP8 + j8];

#pragma unroll
    for (int t = 0; t < 8; t++) {
        const float sf  = s[t];
        const float nzs = -(float)((z >> (4 * t)) & 0xFu) * sf;
        bf16x8 h;
#pragma unroll
        for (int i = 0; i < 8; i++) {
            const float nib = (float)((q[i] >> (4 * t)) & 0xFu);
            h[i] = (__bf16)fmaf(nib, sf, nzs);
        }
        *(int4*)&wt[(size_t)(ncl + t) * K_IN + k0] = __builtin_bit_cast(int4, h);
    }
}

// ---------------------------------------------------------------------------
// r17: register-economical 8-phase 256x256 GEMM (m201 reconstruction).
// BK=64, 8 waves (2M x 4N, wave tile 128x64). LDS recycled at SUB-TILE
// granularity: A[par][quarter] (8KB, freed by each phase's exit barrier),
// B[par][half] (16KB, freed after the step's first phase). One frag set
// live: B (32v) + A-quad (16v) + acc (128v) ~ 200 VGPR, no spill (r16's
// 6.3GB WRITE_SIZE was scratch spill from holding 2 full K-step frag sets).
// Staging 2 loads/thread/phase, issued 4-7 phases ahead; gates at ph0/ph4
// are counted vmcnt(6) (6 newest = next-next step's loads stay in flight).
// ---------------------------------------------------------------------------
#define GLOAD16(gp, lp)                                                        \
    __builtin_amdgcn_global_load_lds(                                          \
        (const __attribute__((address_space(1))) void*)(gp),                   \
        (__attribute__((address_space(3))) void*)(lp), 16, 0, 0)

__global__ __launch_bounds__(512, 1) void gemm_8p_kernel(
    const unsigned short* __restrict__ A,     // xb [M][K] bf16
    const unsigned short* __restrict__ Bt,    // wt chunk [nc][K] bf16
    const float*          __restrict__ bias,  // [N] f32
    float*                __restrict__ C,     // [M][N] f32
    int n_base)
{
    __shared__ __align__(16) unsigned short Alds[2][4][64 * 64];   // 64 KB
    __shared__ __align__(16) unsigned short Blds[2][2][128 * 64];  // 64 KB

    const int tid = threadIdx.x;
    const int l   = tid & 63;
    const int w   = tid >> 6;       // wave 0..7
    const int wm  = w >> 2;         // 0..1
    const int wn  = w & 3;          // 0..3

    // --- bijective XCD swizzle (m204)
    const int nwg = gridDim.x;
    const int q8  = nwg >> 3, r8 = nwg & 7;
    const int xcd = blockIdx.x & 7, idx = blockIdx.x >> 3;
    const int swz = ((xcd < r8) ? xcd * (q8 + 1) : r8 * (q8 + 1) + (xcd - r8) * q8) + idx;
    const int mtile = swz & 31;     // M/256 = 32, M-fastest
    const int ntile = swz >> 5;

    const size_t blockM = (size_t)mtile * 256;
    const int    colc   = ntile * 256;

    const unsigned short* Ag = A  + blockM * K_IN;
    const unsigned short* Bg = Bt + (size_t)colc * K_IN;

    // --- staging roles: 512 thr; 8 thr/row (16B chunks), 64 rows per unit
    const int srow = tid >> 3;              // 0..63 (local row in unit)
    const int cch  = tid & 7;               // physical chunk
    const int kcs  = cch ^ (srow & 7);      // logical chunk (inverse swizzle)
    // A quarter qd: local row r -> global row (r>>5)*128 + 32*qd + (r&31)
    const size_t agrow = (size_t)((srow >> 5) * 128 + (srow & 31)) * K_IN + kcs * 8;
    const size_t bgrow = (size_t)srow * K_IN + kcs * 8;

#define STG_A(par_, qd_, step_)                                                \
    GLOAD16(Ag + agrow + (size_t)(32 * (qd_)) * K_IN + (size_t)(step_) * 64,   \
            &Alds[par_][qd_][(w * 8) * 64])
#define STG_B(par_, hf_, pt_, step_)                                           \
    GLOAD16(Bg + bgrow + (size_t)((hf_) * 128 + (pt_) * 64) * K_IN             \
               + (size_t)(step_) * 64,                                         \
            &Blds[par_][hf_][((pt_) * 64 + w * 8) * 64])

    // --- compute roles
    const int lrow  = l & 15;
    const int lk    = l >> 4;               // 0..3
    const int bhalf = wn >> 1;
    int ach[2];
#pragma unroll
    for (int kk = 0; kk < 2; kk++) ach[kk] = ((kk * 4 + lk) ^ (lrow & 7)) * 8;
    int arow[2];
    arow[0] = (wm * 32 + lrow) * 64;
    arow[1] = (wm * 32 + 16 + lrow) * 64;
    int brow[4];
#pragma unroll
    for (int ni = 0; ni < 4; ni++) brow[ni] = ((wn & 1) * 64 + ni * 16 + lrow) * 64;

    s16x8 Af[2][2], Bf[4][2];
    f32x4 acc[8][4];
#pragma unroll
    for (int i = 0; i < 8; i++)
#pragma unroll
        for (int j = 0; j < 4; j++) acc[i][j] = (f32x4){0.f, 0.f, 0.f, 0.f};

#define RD_B(par_)                                                             \
    do { _Pragma("unroll")                                                     \
        for (int ni = 0; ni < 4; ni++)                                         \
            _Pragma("unroll")                                                  \
            for (int kk = 0; kk < 2; kk++)                                     \
                Bf[ni][kk] = *(const s16x8*)&Blds[par_][bhalf][brow[ni] + ach[kk]]; \
    } while (0)
#define RD_A(par_, c_)                                                         \
    do { _Pragma("unroll")                                                     \
        for (int m2 = 0; m2 < 2; m2++)                                         \
            _Pragma("unroll")                                                  \
            for (int kk = 0; kk < 2; kk++)                                     \
                Af[m2][kk] = *(const s16x8*)&Alds[par_][c_][arow[m2] + ach[kk]]; \
    } while (0)
#define MF(c_)                                                                 \
    do { __builtin_amdgcn_s_setprio(1);                                        \
        _Pragma("unroll")                                                      \
        for (int kk = 0; kk < 2; kk++)                                         \
            _Pragma("unroll")                                                  \
            for (int m2 = 0; m2 < 2; m2++)                                     \
                _Pragma("unroll")                                              \
                for (int ni = 0; ni < 4; ni++)                                 \
                    acc[2 * (c_) + m2][ni] =                                   \
                        __builtin_amdgcn_mfma_f32_16x16x32_bf16(               \
                            __builtin_bit_cast(bf16x8, Af[m2][kk]),            \
                            __builtin_bit_cast(bf16x8, Bf[ni][kk]),            \
                            acc[2 * (c_) + m2][ni], 0, 0, 0);                  \
        __builtin_amdgcn_s_setprio(0); } while (0)

#define BARR() __builtin_amdgcn_s_barrier()
#define SGB()  __builtin_amdgcn_sched_barrier(0)
#define LGK()  asm volatile("s_waitcnt lgkmcnt(0)" ::: "memory")

    const int NT = K_IN / 64;   // 64 K-steps
    const int NI = NT / 2;      // 32 iterations

    // Prologue: step0 fully (8 loads), step1 first 6 (Aq0-2, Bh0x2, Bh1#1).
    STG_A(0, 0, 0); STG_A(0, 1, 0); STG_A(0, 2, 0); STG_A(0, 3, 0);
    STG_B(0, 0, 0, 0); STG_B(0, 0, 1, 0); STG_B(0, 1, 0, 0); STG_B(0, 1, 1, 0);
    STG_A(1, 0, 1); STG_A(1, 1, 1); STG_A(1, 2, 1);
    STG_B(1, 0, 0, 1); STG_B(1, 0, 1, 1); STG_B(1, 1, 0, 1);

    for (int i = 0; i < NI; ++i) {
        const int s1 = 2 * i + 1, s2 = 2 * i + 2, s3 = 2 * i + 3;
        const bool t2 = s2 < NT, t3 = s3 < NT;

        // ph0 (step 2i, par0, quad0) — GATE vmcnt(6)
        asm volatile("s_waitcnt vmcnt(6)" ::: "memory");
        BARR(); SGB();
        RD_B(0); RD_A(0, 0);
        STG_A(1, 3, s1); STG_B(1, 1, 1, s1);     // tail of step s+1
        BARR(); LGK(); SGB();
        MF(0);
        BARR();
        // ph1
        RD_A(0, 1);
        if (t2) { STG_A(0, 0, s2); STG_B(0, 0, 0, s2); }
        BARR(); LGK(); SGB();
        MF(1);
        BARR();
        // ph2
        RD_A(0, 2);
        if (t2) { STG_A(0, 1, s2); STG_B(0, 0, 1, s2); }
        BARR(); LGK(); SGB();
        MF(2);
        BARR();
        // ph3
        RD_A(0, 3);
        if (t2) { STG_A(0, 2, s2); STG_B(0, 1, 0, s2); }
        BARR(); LGK(); SGB();
        MF(3);
        BARR();
        // ph4 (step 2i+1, par1, quad0) — GATE vmcnt(6) (vmcnt(0) last iter)
        if (i < NI - 1) asm volatile("s_waitcnt vmcnt(6)" ::: "memory");
        else            asm volatile("s_waitcnt vmcnt(0)" ::: "memory");
        BARR(); SGB();
        RD_B(1); RD_A(1, 0);
        if (t2) { STG_A(0, 3, s2); STG_B(0, 1, 1, s2); }
        BARR(); LGK(); SGB();
        MF(0);
        BARR();
        // ph5
        RD_A(1, 1);
        if (t3) { STG_A(1, 0, s3); STG_B(1, 0, 0, s3); }
        BARR(); LGK(); SGB();
        MF(1);
        BARR();
        // ph6
        RD_A(1, 2);
        if (t3) { STG_A(1, 1, s3); STG_B(1, 0, 1, s3); }
        BARR(); LGK(); SGB();
        MF(2);
        BARR();
        // ph7
        RD_A(1, 3);
        if (t3) { STG_A(1, 2, s3); STG_B(1, 1, 0, s3); }
        BARR(); LGK(); SGB();
        MF(3);
        BARR();
    }
#undef STG_A
#undef STG_B
#undef RD_A
#undef RD_B
#undef MF
#undef BARR
#undef SGB
#undef LGK

    // Epilogue: C/D layout col = lane&15, row = (lane>>4)*4 + reg (m89)
#pragma unroll
    for (int ni = 0; ni < 4; ++ni) {
        const int ng = n_base + colc + wn * 64 + ni * 16 + lrow;
        const float bv = bias[ng];
#pragma unroll
        for (int mi = 0; mi < 8; ++mi) {
            f32x4 v = acc[mi][ni];
#pragma unroll
            for (int r = 0; r < 4; r++) {
                const size_t grow = blockM + wm * 128 + mi * 16 + lk * 4 + r;
                C[grow * N_OUT + ng] = v[r] + bv;
            }
        }
    }
}

// ---------------------------------------------------------------------------
// Fallback: fully fused kernel (passed round 4, verbatim).
// ---------------------------------------------------------------------------
__global__ __launch_bounds__(256) void fused_w4a16_kernel(
    const float*        __restrict__ A,
    const unsigned int* __restrict__ qw,
    const unsigned int* __restrict__ qz,
    const float*        __restrict__ sc,
    const float*        __restrict__ bias,
    float*              __restrict__ C)
{
    __shared__ __align__(16) unsigned short As[128 * 64];
    __shared__ __align__(16) unsigned short Bs[128 * 64];

    const int tid = threadIdx.x;
    const int l   = tid & 63;
    const int w   = tid >> 6;
    const int wm  = w >> 1;
    const int wn  = w & 1;
    const size_t blockM = (size_t)blockIdx.x * 128;
    const int    colN   = blockIdx.y * 128;

    const float* Ag = A + blockM * K_IN;

    const int r_in = l >> 3;
    const int cch  = l & 7;
    int    aw_off[4];
    size_t ag_off[4];
#pragma unroll
    for (int qq = 0; qq < 4; qq++) {
        const int row = w * 32 + qq * 8 + r_in;
        aw_off[qq] = row * 64 + ((cch ^ r_in) * 8);
        ag_off[qq] = (size_t)row * K_IN + cch * 8;
    }

    const int kc = tid & 7;
    int ngl[4], j8[4], shn[4], bs_off[4];
#pragma unroll
    for (int p = 0; p < 4; p++) {
        const int nl = p * 32 + (tid >> 3);
        const int ng = colN + nl;
        ngl[p]    = ng;
        j8[p]     = ng >> 3;
        shn[p]    = 4 * (ng & 7);
        bs_off[p] = nl * 64 + ((kc ^ (nl & 7)) * 8);
    }

    f32x4 acc[4][4];
#pragma unroll
    for (int i = 0; i < 4; i++)
#pragma unroll
        for (int j = 0; j < 4; j++) acc[i][j] = (f32x4){0.f, 0.f, 0.f, 0.f};

    const int lrow = l & 15;
    const int lk   = l >> 4;
    const int NT   = K_IN / 64;

    for (int kt = 0; kt < NT; ++kt) {
        const int K0 = kt * 64;
        const int g  = K0 >> 7;

        float4 fa[4][2];
#pragma unroll
        for (int qq = 0; qq < 4; qq++) {
            fa[qq][0] = *(const float4*)(Ag + ag_off[qq] + K0);
            fa[qq][1] = *(const float4*)(Ag + ag_off[qq] + K0 + 4);
        }

        unsigned int q[4][8];
        float sf[4], nzs[4];
#pragma unroll
        for (int p = 0; p < 4; p++) {
            const unsigned int* qp = qw + (size_t)(K0 + kc * 8) * NP8 + j8[p];
#pragma unroll
            for (int i = 0; i < 8; i++) q[p][i] = qp[(size_t)i * NP8];
            const float zf = (float)((qz[(size_t)g * NP8 + j8[p]] >> shn[p]) & 0xFu);
            sf[p]  = sc[(size_t)g * N_OUT + ngl[p]];
            nzs[p] = -zf * sf[p];
        }

        __syncthreads();

#pragma unroll
        for (int qq = 0; qq < 4; qq++) {
            bf16x8 h;
#pragma unroll
            for (int i = 0; i < 4; i++) {
                h[i]     = (__bf16)(((const float*)&fa[qq][0])[i]);
                h[i + 4] = (__bf16)(((const float*)&fa[qq][1])[i]);
            }
            *(int4*)&As[aw_off[qq]] = __builtin_bit_cast(int4, h);
        }
#pragma unroll
        for (int p = 0; p < 4; p++) {
            bf16x8 h;
#pragma unroll
            for (int i = 0; i < 8; i++) {
                const float nib = (float)((q[p][i] >> shn[p]) & 0xFu);
                h[i] = (__bf16)fmaf(nib, sf[p], nzs[p]);
            }
            *(int4*)&Bs[bs_off[p]] = __builtin_bit_cast(int4, h);
        }

        __syncthreads();

#pragma unroll
        for (int ks = 0; ks < 2; ++ks) {
            s16x8 a[4], b[4];
            const int kcc = ks * 4 + lk;
#pragma unroll
            for (int mi = 0; mi < 4; mi++) {
                const int row = wm * 64 + mi * 16 + lrow;
                a[mi] = *(const s16x8*)&As[row * 64 + ((kcc ^ (row & 7)) * 8)];
            }
#pragma unroll
            for (int ni = 0; ni < 4; ni++) {
                const int row = wn * 64 + ni * 16 + lrow;
                b[ni] = *(const s16x8*)&Bs[row * 64 + ((kcc ^ (row & 7)) * 8)];
            }
#pragma unroll
            for (int mi = 0; mi < 4; mi++)
#pragma unroll
                for (int ni = 0; ni < 4; ni++)
                    acc[mi][ni] = __builtin_amdgcn_mfma_f32_16x16x32_bf16(
                        __builtin_bit_cast(bf16x8, a[mi]),
                        __builtin_bit_cast(bf16x8, b[ni]),
                        acc[mi][ni], 0, 0, 0);
        }
    }

#pragma unroll
    for (int ni = 0; ni < 4; ++ni) {
        const int ng = colN + wn * 64 + ni * 16 + lrow;
        const float bv = bias[ng];
#pragma unroll
        for (int mi = 0; mi < 4; ++mi) {
            f32x4 v = acc[mi][ni];
#pragma unroll
            for (int r = 0; r < 4; r++) {
                const size_t grow = blockM + wm * 64 + mi * 16 + lk * 4 + r;
                C[grow * N_OUT + ng] = v[r] + bv;
            }
        }
    }
}

// ---------------------------------------------------------------------------
extern "C" void kernel_launch(void* const* d_in, const int* in_sizes, int n_in,
                              void* d_out, int out_size, void* d_ws, size_t ws_size,
                              hipStream_t stream)
{
    const float*        x    = (const float*)d_in[0];
    const unsigned int* qw   = (const unsigned int*)d_in[1];
    const unsigned int* qz   = (const unsigned int*)d_in[2];
    const float*        sc   = (const float*)d_in[3];
    const float*        bias = (const float*)d_in[4];
    float*              out  = (float*)d_out;

    const size_t XBF    = (size_t)M_TOK * K_IN * 2;   // 64 MiB bf16 x
    const size_t COL256 = (size_t)256 * K_IN * 2;     // 2 MiB per 256 cols W^T

    if (ws_size >= XBF + COL256) {
        unsigned short* xb = (unsigned short*)d_ws;
        unsigned short* wt = (unsigned short*)((char*)d_ws + XBF);
        const long n8 = (long)M_TOK * K_IN / 8;
        convert_x_kernel<<<2048, 256, 0, stream>>>(x, xb, n8);

        size_t chunk_cols = ((ws_size - XBF) / COL256) * 256;
        if (chunk_cols > (size_t)N_OUT) chunk_cols = N_OUT;
        for (int n0 = 0; n0 < N_OUT; n0 += (int)chunk_cols) {
            int nc = N_OUT - n0;
            if (nc > (int)chunk_cols) nc = (int)chunk_cols;
            dequant_kernel<<<dim3(K_IN / GS, nc / 128), 256, 0, stream>>>(qw, qz, sc, wt, n0);
            gemm_8p_kernel<<<32 * (nc / 256), 512, 0, stream>>>(xb, wt, bias, out, n0);
        }
    } else {
        fused_w4a16_kernel<<<dim3(M_TOK / 128, N_OUT / 128), 256, 0, stream>>>(
            x, qw, qz, sc, bias, out);
    }
}

// Round 18
// 842.986 us; speedup vs baseline: 3.5785x; 1.0176x over previous
//
#include <hip/hip_runtime.h>
#include <hip/hip_bf16.h>
#include <cstdint>

// Problem constants (match reference)
#define M_TOK 8192
#define K_IN  4096
#define N_OUT 11008
#define NP8   (N_OUT / 8)
#define GS    128

// DTYPE CONTRACT (verified round 4): x/scales/bias/out are float32 on device;
// qweight/qzeros are int32.

typedef __attribute__((ext_vector_type(8))) short  s16x8;
typedef __attribute__((ext_vector_type(8))) __bf16 bf16x8;
typedef __attribute__((ext_vector_type(4))) float  f32x4;

// ---------------------------------------------------------------------------
__global__ __launch_bounds__(256) void convert_x_kernel(
    const float* __restrict__ in, unsigned short* __restrict__ outp, long n8)
{
    long i = (long)blockIdx.x * blockDim.x + threadIdx.x;
    const long stride = (long)gridDim.x * blockDim.x;
    for (; i < n8; i += stride) {
        const float4 a = ((const float4*)in)[2 * i];
        const float4 b = ((const float4*)in)[2 * i + 1];
        bf16x8 h;
        h[0] = (__bf16)a.x; h[1] = (__bf16)a.y; h[2] = (__bf16)a.z; h[3] = (__bf16)a.w;
        h[4] = (__bf16)b.x; h[5] = (__bf16)b.y; h[6] = (__bf16)b.z; h[7] = (__bf16)b.w;
        ((int4*)outp)[i] = __builtin_bit_cast(int4, h);
    }
}

// ---------------------------------------------------------------------------
__global__ __launch_bounds__(256) void dequant_kernel(
    const unsigned int* __restrict__ qw,
    const unsigned int* __restrict__ qz,
    const float*        __restrict__ sc,
    unsigned short*     __restrict__ wt,
    int n_base)
{
    const int tid = threadIdx.x;
    const int k8  = tid & 15;
    const int n8  = tid >> 4;
    const int g   = blockIdx.x;
    const int k0  = g * GS + k8 * 8;
    const int ncl = blockIdx.y * 128 + n8 * 8;
    const int ng  = n_base + ncl;
    const int j8  = ng >> 3;

    const unsigned int z = qz[(size_t)g * NP8 + j8];

    float s[8];
    *(float4*)&s[0] = *(const float4*)&sc[(size_t)g * N_OUT + ng];
    *(float4*)&s[4] = *(const float4*)&sc[(size_t)g * N_OUT + ng + 4];

    unsigned int q[8];
#pragma unroll
    for (int i = 0; i < 8; i++) q[i] = qw[(size_t)(k0 + i) * NP8 + j8];

#pragma unroll
    for (int t = 0; t < 8; t++) {
        const float sf  = s[t];
        const float nzs = -(float)((z >> (4 * t)) & 0xFu) * sf;
        bf16x8 h;
#pragma unroll
        for (int i = 0; i < 8; i++) {
            const float nib = (float)((q[i] >> (4 * t)) & 0xFu);
            h[i] = (__bf16)fmaf(nib, sf, nzs);
        }
        *(int4*)&wt[(size_t)(ncl + t) * K_IN + k0] = __builtin_bit_cast(int4, h);
    }
}

// ---------------------------------------------------------------------------
// r18: read-ahead 8-phase 256x256 GEMM. Same LDS layout/staging/gates as r17
// (proven: absmax 0.125, conflicts 0, no spill). CHANGE: ds_reads at phase p
// feed MFMAs at phase p+1 (AX/AY A-quad ping-pong, Bf0/Bf1 per parity);
// NO explicit lgkmcnt — compiler auto-inserts partial waits at first use,
// one barrier+phase later => read latency hides under MFMA+stage. Safety:
// all par0 data vmcnt(6)-resident at ph0 gate, par1 at ph4 gate; any read
// after its parity's gate is race-free; slot re-stage is >=1 barrier after
// the slot's read. 10 barriers/iter (was 16).
// ---------------------------------------------------------------------------
#define GLOAD16(gp, lp)                                                        \
    __builtin_amdgcn_global_load_lds(                                          \
        (const __attribute__((address_space(1))) void*)(gp),                   \
        (__attribute__((address_space(3))) void*)(lp), 16, 0, 0)

__global__ __launch_bounds__(512, 1) void gemm_8pv2_kernel(
    const unsigned short* __restrict__ A,     // xb [M][K] bf16
    const unsigned short* __restrict__ Bt,    // wt chunk [nc][K] bf16
    const float*          __restrict__ bias,  // [N] f32
    float*                __restrict__ C,     // [M][N] f32
    int n_base)
{
    __shared__ __align__(16) unsigned short Alds[2][4][64 * 64];   // 64 KB
    __shared__ __align__(16) unsigned short Blds[2][2][128 * 64];  // 64 KB

    const int tid = threadIdx.x;
    const int l   = tid & 63;
    const int w   = tid >> 6;       // wave 0..7
    const int wm  = w >> 2;         // 0..1
    const int wn  = w & 3;          // 0..3

    // --- bijective XCD swizzle (m204)
    const int nwg = gridDim.x;
    const int q8  = nwg >> 3, r8 = nwg & 7;
    const int xcd = blockIdx.x & 7, idx = blockIdx.x >> 3;
    const int swz = ((xcd < r8) ? xcd * (q8 + 1) : r8 * (q8 + 1) + (xcd - r8) * q8) + idx;
    const int mtile = swz & 31;
    const int ntile = swz >> 5;

    const size_t blockM = (size_t)mtile * 256;
    const int    colc   = ntile * 256;

    const unsigned short* Ag = A  + blockM * K_IN;
    const unsigned short* Bg = Bt + (size_t)colc * K_IN;

    // --- staging roles (r17-proven)
    const int srow = tid >> 3;
    const int cch  = tid & 7;
    const int kcs  = cch ^ (srow & 7);
    const size_t agrow = (size_t)((srow >> 5) * 128 + (srow & 31)) * K_IN + kcs * 8;
    const size_t bgrow = (size_t)srow * K_IN + kcs * 8;

#define STG_A(par_, qd_, step_)                                                \
    GLOAD16(Ag + agrow + (size_t)(32 * (qd_)) * K_IN + (size_t)(step_) * 64,   \
            &Alds[par_][qd_][(w * 8) * 64])
#define STG_B(par_, hf_, pt_, step_)                                           \
    GLOAD16(Bg + bgrow + (size_t)((hf_) * 128 + (pt_) * 64) * K_IN             \
               + (size_t)(step_) * 64,                                         \
            &Blds[par_][hf_][((pt_) * 64 + w * 8) * 64])

    // --- compute roles (r17-proven)
    const int lrow  = l & 15;
    const int lk    = l >> 4;
    const int bhalf = wn >> 1;
    int ach[2];
#pragma unroll
    for (int kk = 0; kk < 2; kk++) ach[kk] = ((kk * 4 + lk) ^ (lrow & 7)) * 8;
    int arow[2];
    arow[0] = (wm * 32 + lrow) * 64;
    arow[1] = (wm * 32 + 16 + lrow) * 64;
    int brow[4];
#pragma unroll
    for (int ni = 0; ni < 4; ni++) brow[ni] = ((wn & 1) * 64 + ni * 16 + lrow) * 64;

    s16x8 AX[2][2], AY[2][2], Bf0[4][2], Bf1[4][2];
    f32x4 acc[8][4];
#pragma unroll
    for (int i = 0; i < 8; i++)
#pragma unroll
        for (int j = 0; j < 4; j++) acc[i][j] = (f32x4){0.f, 0.f, 0.f, 0.f};

#define RD_B(dst, par_)                                                        \
    do { _Pragma("unroll")                                                     \
        for (int ni = 0; ni < 4; ni++)                                         \
            _Pragma("unroll")                                                  \
            for (int kk = 0; kk < 2; kk++)                                     \
                dst[ni][kk] = *(const s16x8*)&Blds[par_][bhalf][brow[ni] + ach[kk]]; \
    } while (0)
#define RD_A(dst, par_, c_)                                                    \
    do { _Pragma("unroll")                                                     \
        for (int m2 = 0; m2 < 2; m2++)                                         \
            _Pragma("unroll")                                                  \
            for (int kk = 0; kk < 2; kk++)                                     \
                dst[m2][kk] = *(const s16x8*)&Alds[par_][c_][arow[m2] + ach[kk]]; \
    } while (0)
#define MF(ASET, BSET, c_)                                                     \
    do { __builtin_amdgcn_s_setprio(1);                                        \
        _Pragma("unroll")                                                      \
        for (int kk = 0; kk < 2; kk++)                                         \
            _Pragma("unroll")                                                  \
            for (int m2 = 0; m2 < 2; m2++)                                     \
                _Pragma("unroll")                                              \
                for (int ni = 0; ni < 4; ni++)                                 \
                    acc[2 * (c_) + m2][ni] =                                   \
                        __builtin_amdgcn_mfma_f32_16x16x32_bf16(               \
                            __builtin_bit_cast(bf16x8, ASET[m2][kk]),          \
                            __builtin_bit_cast(bf16x8, BSET[ni][kk]),          \
                            acc[2 * (c_) + m2][ni], 0, 0, 0);                  \
        __builtin_amdgcn_s_setprio(0); } while (0)

#define BARR() __builtin_amdgcn_s_barrier()
#define SGB()  __builtin_amdgcn_sched_barrier(0)

    const int NT = K_IN / 64;   // 64 K-steps
    const int NI = NT / 2;      // 32 iterations

    // Prologue: step0 fully (8 loads), step1 first 6.
    STG_A(0, 0, 0); STG_A(0, 1, 0); STG_A(0, 2, 0); STG_A(0, 3, 0);
    STG_B(0, 0, 0, 0); STG_B(0, 0, 1, 0); STG_B(0, 1, 0, 0); STG_B(0, 1, 1, 0);
    STG_A(1, 0, 1); STG_A(1, 1, 1); STG_A(1, 2, 1);
    STG_B(1, 0, 0, 1); STG_B(1, 0, 1, 1); STG_B(1, 1, 0, 1);

    // iter0 ph0: gate par0; read B0 + A quad0; stage par1 tail of step 1.
    asm volatile("s_waitcnt vmcnt(6)" ::: "memory");
    BARR(); SGB();
    RD_B(Bf0, 0); RD_A(AX, 0, 0);
    STG_A(1, 3, 1); STG_B(1, 1, 1, 1);
    BARR();

    for (int i = 0; i < NI; ++i) {
        const int s2 = 2 * i + 2, s3 = 2 * i + 3;
        const bool t2 = s2 < NT, t3 = s3 < NT;

        // ph1: read A q1 (for ph2); stage s2; MFMA q0 (AX read @ph0)
        RD_A(AY, 0, 1);
        if (t2) { STG_A(0, 0, s2); STG_B(0, 0, 0, s2); }
        BARR();
        MF(AX, Bf0, 0);
        // ph2
        RD_A(AX, 0, 2);
        if (t2) { STG_A(0, 1, s2); STG_B(0, 0, 1, s2); }
        BARR();
        MF(AY, Bf0, 1);
        // ph3
        RD_A(AY, 0, 3);
        if (t2) { STG_A(0, 2, s2); STG_B(0, 1, 0, s2); }
        BARR();
        MF(AX, Bf0, 2);
        // ph4: GATE par1; read B1 + A(1,q0); stage s2 tail; MFMA q3 of par0
        if (i < NI - 1) asm volatile("s_waitcnt vmcnt(6)" ::: "memory");
        else            asm volatile("s_waitcnt vmcnt(0)" ::: "memory");
        BARR(); SGB();
        RD_B(Bf1, 1); RD_A(AX, 1, 0);
        if (t2) { STG_A(0, 3, s2); STG_B(0, 1, 1, s2); }
        BARR();
        MF(AY, Bf0, 3);
        // ph5
        RD_A(AY, 1, 1);
        if (t3) { STG_A(1, 0, s3); STG_B(1, 0, 0, s3); }
        BARR();
        MF(AX, Bf1, 0);
        // ph6
        RD_A(AX, 1, 2);
        if (t3) { STG_A(1, 1, s3); STG_B(1, 0, 1, s3); }
        BARR();
        MF(AY, Bf1, 1);
        // ph7
        RD_A(AY, 1, 3);
        if (t3) { STG_A(1, 2, s3); STG_B(1, 1, 0, s3); }
        BARR();
        MF(AX, Bf1, 2);
        // ph0' (primes iter i+1): gate par0(next); read B0+A(0,q0); stage s3 tail
        if (i < NI - 1) {
            asm volatile("s_waitcnt vmcnt(6)" ::: "memory");
            BARR(); SGB();
            RD_B(Bf0, 0); RD_A(AX, 0, 0);
            STG_A(1, 3, s3); STG_B(1, 1, 1, s3);
            BARR();
            MF(AY, Bf1, 3);
        }
    }
    // final MFMA: q3 of the last par1 (AY read at last ph7)
    MF(AY, Bf1, 3);
#undef STG_A
#undef STG_B
#undef RD_A
#undef RD_B
#undef MF
#undef BARR
#undef SGB

    // Epilogue: C/D layout col = lane&15, row = (lane>>4)*4 + reg (m89)
#pragma unroll
    for (int ni = 0; ni < 4; ++ni) {
        const int ng = n_base + colc + wn * 64 + ni * 16 + lrow;
        const float bv = bias[ng];
#pragma unroll
        for (int mi = 0; mi < 8; ++mi) {
            f32x4 v = acc[mi][ni];
#pragma unroll
            for (int r = 0; r < 4; r++) {
                const size_t grow = blockM + wm * 128 + mi * 16 + lk * 4 + r;
                C[grow * N_OUT + ng] = v[r] + bv;
            }
        }
    }
}

// ---------------------------------------------------------------------------
// Fallback: fully fused kernel (passed round 4, verbatim).
// ---------------------------------------------------------------------------
__global__ __launch_bounds__(256) void fused_w4a16_kernel(
    const float*        __restrict__ A,
    const unsigned int* __restrict__ qw,
    const unsigned int* __restrict__ qz,
    const float*        __restrict__ sc,
    const float*        __restrict__ bias,
    float*              __restrict__ C)
{
    __shared__ __align__(16) unsigned short As[128 * 64];
    __shared__ __align__(16) unsigned short Bs[128 * 64];

    const int tid = threadIdx.x;
    const int l   = tid & 63;
    const int w   = tid >> 6;
    const int wm  = w >> 1;
    const int wn  = w & 1;
    const size_t blockM = (size_t)blockIdx.x * 128;
    const int    colN   = blockIdx.y * 128;

    const float* Ag = A + blockM * K_IN;

    const int r_in = l >> 3;
    const int cch  = l & 7;
    int    aw_off[4];
    size_t ag_off[4];
#pragma unroll
    for (int qq = 0; qq < 4; qq++) {
        const int row = w * 32 + qq * 8 + r_in;
        aw_off[qq] = row * 64 + ((cch ^ r_in) * 8);
        ag_off[qq] = (size_t)row * K_IN + cch * 8;
    }

    const int kc = tid & 7;
    int ngl[4], j8[4], shn[4], bs_off[4];
#pragma unroll
    for (int p = 0; p < 4; p++) {
        const int nl = p * 32 + (tid >> 3);
        const int ng = colN + nl;
        ngl[p]    = ng;
        j8[p]     = ng >> 3;
        shn[p]    = 4 * (ng & 7);
        bs_off[p] = nl * 64 + ((kc ^ (nl & 7)) * 8);
    }

    f32x4 acc[4][4];
#pragma unroll
    for (int i = 0; i < 4; i++)
#pragma unroll
        for (int j = 0; j < 4; j++) acc[i][j] = (f32x4){0.f, 0.f, 0.f, 0.f};

    const int lrow = l & 15;
    const int lk   = l >> 4;
    const int NT   = K_IN / 64;

    for (int kt = 0; kt < NT; ++kt) {
        const int K0 = kt * 64;
        const int g  = K0 >> 7;

        float4 fa[4][2];
#pragma unroll
        for (int qq = 0; qq < 4; qq++) {
            fa[qq][0] = *(const float4*)(Ag + ag_off[qq] + K0);
            fa[qq][1] = *(const float4*)(Ag + ag_off[qq] + K0 + 4);
        }

        unsigned int q[4][8];
        float sf[4], nzs[4];
#pragma unroll
        for (int p = 0; p < 4; p++) {
            const unsigned int* qp = qw + (size_t)(K0 + kc * 8) * NP8 + j8[p];
#pragma unroll
            for (int i = 0; i < 8; i++) q[p][i] = qp[(size_t)i * NP8];
            const float zf = (float)((qz[(size_t)g * NP8 + j8[p]] >> shn[p]) & 0xFu);
            sf[p]  = sc[(size_t)g * N_OUT + ngl[p]];
            nzs[p] = -zf * sf[p];
        }

        __syncthreads();

#pragma unroll
        for (int qq = 0; qq < 4; qq++) {
            bf16x8 h;
#pragma unroll
            for (int i = 0; i < 4; i++) {
                h[i]     = (__bf16)(((const float*)&fa[qq][0])[i]);
                h[i + 4] = (__bf16)(((const float*)&fa[qq][1])[i]);
            }
            *(int4*)&As[aw_off[qq]] = __builtin_bit_cast(int4, h);
        }
#pragma unroll
        for (int p = 0; p < 4; p++) {
            bf16x8 h;
#pragma unroll
            for (int i = 0; i < 8; i++) {
                const float nib = (float)((q[p][i] >> shn[p]) & 0xFu);
                h[i] = (__bf16)fmaf(nib, sf[p], nzs[p]);
            }
            *(int4*)&Bs[bs_off[p]] = __builtin_bit_cast(int4, h);
        }

        __syncthreads();

#pragma unroll
        for (int ks = 0; ks < 2; ++ks) {
            s16x8 a[4], b[4];
            const int kcc = ks * 4 + lk;
#pragma unroll
            for (int mi = 0; mi < 4; mi++) {
                const int row = wm * 64 + mi * 16 + lrow;
                a[mi] = *(const s16x8*)&As[row * 64 + ((kcc ^ (row & 7)) * 8)];
            }
#pragma unroll
            for (int ni = 0; ni < 4; ni++) {
                const int row = wn * 64 + ni * 16 + lrow;
                b[ni] = *(const s16x8*)&Bs[row * 64 + ((kcc ^ (row & 7)) * 8)];
            }
#pragma unroll
            for (int mi = 0; mi < 4; mi++)
#pragma unroll
                for (int ni = 0; ni < 4; ni++)
                    acc[mi][ni] = __builtin_amdgcn_mfma_f32_16x16x32_bf16(
                        __builtin_bit_cast(bf16x8, a[mi]),
                        __builtin_bit_cast(bf16x8, b[ni]),
                        acc[mi][ni], 0, 0, 0);
        }
    }

#pragma unroll
    for (int ni = 0; ni < 4; ++ni) {
        const int ng = colN + wn * 64 + ni * 16 + lrow;
        const float bv = bias[ng];
#pragma unroll
        for (int mi = 0; mi < 4; ++mi) {
            f32x4 v = acc[mi][ni];
#pragma unroll
            for (int r = 0; r < 4; r++) {
                const size_t grow = blockM + wm * 64 + mi * 16 + lk * 4 + r;
                C[grow * N_OUT + ng] = v[r] + bv;
            }
        }
    }
}

// ---------------------------------------------------------------------------
extern "C" void kernel_launch(void* const* d_in, const int* in_sizes, int n_in,
                              void* d_out, int out_size, void* d_ws, size_t ws_size,
                              hipStream_t stream)
{
    const float*        x    = (const float*)d_in[0];
    const unsigned int* qw   = (const unsigned int*)d_in[1];
    const unsigned int* qz   = (const unsigned int*)d_in[2];
    const float*        sc   = (const float*)d_in[3];
    const float*        bias = (const float*)d_in[4];
    float*              out  = (float*)d_out;

    const size_t XBF    = (size_t)M_TOK * K_IN * 2;   // 64 MiB bf16 x
    const size_t COL256 = (size_t)256 * K_IN * 2;     // 2 MiB per 256 cols W^T

    if (ws_size >= XBF + COL256) {
        unsigned short* xb = (unsigned short*)d_ws;
        unsigned short* wt = (unsigned short*)((char*)d_ws + XBF);
        const long n8 = (long)M_TOK * K_IN / 8;
        convert_x_kernel<<<2048, 256, 0, stream>>>(x, xb, n8);

        size_t chunk_cols = ((ws_size - XBF) / COL256) * 256;
        if (chunk_cols > (size_t)N_OUT) chunk_cols = N_OUT;
        for (int n0 = 0; n0 < N_OUT; n0 += (int)chunk_cols) {
            int nc = N_OUT - n0;
            if (nc > (int)chunk_cols) nc = (int)chunk_cols;
            dequant_kernel<<<dim3(K_IN / GS, nc / 128), 256, 0, stream>>>(qw, qz, sc, wt, n0);
            gemm_8pv2_kernel<<<32 * (nc / 256), 512, 0, stream>>>(xb, wt, bias, out, n0);
        }
    } else {
        fused_w4a16_kernel<<<dim3(M_TOK / 128, N_OUT / 128), 256, 0, stream>>>(
            x, qw, qz, sc, bias, out);
    }
}

// Round 19
// 819.147 us; speedup vs baseline: 3.6827x; 1.0291x over previous
//
#include <hip/hip_runtime.h>
#include <hip/hip_bf16.h>
#include <cstdint>

// Problem constants (match reference)
#define M_TOK 8192
#define K_IN  4096
#define N_OUT 11008
#define NP8   (N_OUT / 8)
#define GS    128

// DTYPE CONTRACT (verified round 4): x/scales/bias/out are float32 on device;
// qweight/qzeros are int32.

typedef __attribute__((ext_vector_type(8)))  short  s16x8;
typedef __attribute__((ext_vector_type(8)))  __bf16 bf16x8;
typedef __attribute__((ext_vector_type(4)))  float  f32x4;
typedef __attribute__((ext_vector_type(16))) float  f32x16;

// ---------------------------------------------------------------------------
__global__ __launch_bounds__(256) void convert_x_kernel(
    const float* __restrict__ in, unsigned short* __restrict__ outp, long n8)
{
    long i = (long)blockIdx.x * blockDim.x + threadIdx.x;
    const long stride = (long)gridDim.x * blockDim.x;
    for (; i < n8; i += stride) {
        const float4 a = ((const float4*)in)[2 * i];
        const float4 b = ((const float4*)in)[2 * i + 1];
        bf16x8 h;
        h[0] = (__bf16)a.x; h[1] = (__bf16)a.y; h[2] = (__bf16)a.z; h[3] = (__bf16)a.w;
        h[4] = (__bf16)b.x; h[5] = (__bf16)b.y; h[6] = (__bf16)b.z; h[7] = (__bf16)b.w;
        ((int4*)outp)[i] = __builtin_bit_cast(int4, h);
    }
}

// ---------------------------------------------------------------------------
__global__ __launch_bounds__(256) void dequant_kernel(
    const unsigned int* __restrict__ qw,
    const unsigned int* __restrict__ qz,
    const float*        __restrict__ sc,
    unsigned short*     __restrict__ wt,
    int n_base)
{
    const int tid = threadIdx.x;
    const int k8  = tid & 15;
    const int n8  = tid >> 4;
    const int g   = blockIdx.x;
    const int k0  = g * GS + k8 * 8;
    const int ncl = blockIdx.y * 128 + n8 * 8;
    const int ng  = n_base + ncl;
    const int j8  = ng >> 3;

    const unsigned int z = qz[(size_t)g * NP8 + j8];

    float s[8];
    *(float4*)&s[0] = *(const float4*)&sc[(size_t)g * N_OUT + ng];
    *(float4*)&s[4] = *(const float4*)&sc[(size_t)g * N_OUT + ng + 4];

    unsigned int q[8];
#pragma unroll
    for (int i = 0; i < 8; i++) q[i] = qw[(size_t)(k0 + i) * NP8 + j8];

#pragma unroll
    for (int t = 0; t < 8; t++) {
        const float sf  = s[t];
        const float nzs = -(float)((z >> (4 * t)) & 0xFu) * sf;
        bf16x8 h;
#pragma unroll
        for (int i = 0; i < 8; i++) {
            const float nib = (float)((q[i] >> (4 * t)) & 0xFu);
            h[i] = (__bf16)fmaf(nib, sf, nzs);
        }
        *(int4*)&wt[(size_t)(ncl + t) * K_IN + k0] = __builtin_bit_cast(int4, h);
    }
}

// ---------------------------------------------------------------------------
// r19: r18's proven 8-phase skeleton with 32x32x16 MFMA (2382 vs 2075 TF
// ceiling, half the MFMA instructions, 8 independent MFMAs/phase).
// A-quarter q = global rows {32q..32q+31} u {128+32q..+31}; quad==mb,
// row-in-quarter = wm*32+ln31 (r&7==l&7 -> same proven swizzle).
// Phase p reads A quad p (read-ahead); stage Aq_p at phase p+1; B read
// all-at-gate, staged ph1-4. Gates vmcnt(6) by r17's 8-issue-window
// accounting. Gate phases do MFMA FIRST so only one B-frag set is live.
// ---------------------------------------------------------------------------
#define GLOAD16(gp, lp)                                                        \
    __builtin_amdgcn_global_load_lds(                                          \
        (const __attribute__((address_space(1))) void*)(gp),                   \
        (__attribute__((address_space(3))) void*)(lp), 16, 0, 0)

__global__ __launch_bounds__(512, 1) void gemm_8pw_kernel(
    const unsigned short* __restrict__ A,     // xb [M][K] bf16
    const unsigned short* __restrict__ Bt,    // wt chunk [nc][K] bf16
    const float*          __restrict__ bias,  // [N] f32
    float*                __restrict__ C,     // [M][N] f32
    int n_base)
{
    __shared__ __align__(16) unsigned short Alds[2][4][64 * 64];   // 64 KB
    __shared__ __align__(16) unsigned short Blds[2][2][128 * 64];  // 64 KB

    const int tid = threadIdx.x;
    const int l   = tid & 63;
    const int w   = tid >> 6;       // wave 0..7
    const int wm  = w >> 2;         // 0..1
    const int wn  = w & 3;          // 0..3

    // --- bijective XCD swizzle (m204)
    const int nwg = gridDim.x;
    const int q8  = nwg >> 3, r8 = nwg & 7;
    const int xcd = blockIdx.x & 7, idx = blockIdx.x >> 3;
    const int swz = ((xcd < r8) ? xcd * (q8 + 1) : r8 * (q8 + 1) + (xcd - r8) * q8) + idx;
    const int mtile = swz & 31;
    const int ntile = swz >> 5;

    const size_t blockM = (size_t)mtile * 256;
    const int    colc   = ntile * 256;

    const unsigned short* Ag = A  + blockM * K_IN;
    const unsigned short* Bg = Bt + (size_t)colc * K_IN;

    // --- staging roles (r17/r18-proven)
    const int srow = tid >> 3;
    const int cch  = tid & 7;
    const int kcs  = cch ^ (srow & 7);
    const size_t agrow = (size_t)((srow >> 5) * 128 + (srow & 31)) * K_IN + kcs * 8;
    const size_t bgrow = (size_t)srow * K_IN + kcs * 8;

#define STG_A(par_, qd_, step_)                                                \
    GLOAD16(Ag + agrow + (size_t)(32 * (qd_)) * K_IN + (size_t)(step_) * 64,   \
            &Alds[par_][qd_][(w * 8) * 64])
#define STG_B(par_, hf_, pt_, step_)                                           \
    GLOAD16(Bg + bgrow + (size_t)((hf_) * 128 + (pt_) * 64) * K_IN             \
               + (size_t)(step_) * 64,                                         \
            &Blds[par_][hf_][((pt_) * 64 + w * 8) * 64])

    // --- compute roles (32x32x16)
    const int ln31  = l & 31;
    const int kh    = l >> 5;               // 0..1: k = ks*16 + kh*8 + e
    const int bhalf = wn >> 1;
    int ach[4];
#pragma unroll
    for (int ks = 0; ks < 4; ks++) ach[ks] = ((ks * 2 + kh) ^ (l & 7)) * 8;
    const int arow = (wm * 32 + ln31) * 64;           // row-in-quarter
    int brow[2];
#pragma unroll
    for (int nb = 0; nb < 2; nb++)
        brow[nb] = ((wn & 1) * 64 + nb * 32 + ln31) * 64;

    s16x8 AX[4], AY[4], Bf[4][2];
    f32x16 acc[4][2];
#pragma unroll
    for (int i = 0; i < 4; i++)
#pragma unroll
        for (int j = 0; j < 2; j++)
#pragma unroll
            for (int e = 0; e < 16; e++) acc[i][j][e] = 0.f;

#define RD_A(dst, par_, mb_)                                                   \
    do { _Pragma("unroll")                                                     \
        for (int ks = 0; ks < 4; ks++)                                         \
            dst[ks] = *(const s16x8*)&Alds[par_][mb_][arow + ach[ks]];         \
    } while (0)
#define RD_B(par_)                                                             \
    do { _Pragma("unroll")                                                     \
        for (int ks = 0; ks < 4; ks++)                                         \
            _Pragma("unroll")                                                  \
            for (int nb = 0; nb < 2; nb++)                                     \
                Bf[ks][nb] = *(const s16x8*)&Blds[par_][bhalf][brow[nb] + ach[ks]]; \
    } while (0)
#define MF(mb_, ASET)                                                          \
    do { __builtin_amdgcn_s_setprio(1);                                        \
        _Pragma("unroll")                                                      \
        for (int ks = 0; ks < 4; ks++)                                         \
            _Pragma("unroll")                                                  \
            for (int nb = 0; nb < 2; nb++)                                     \
                acc[mb_][nb] = __builtin_amdgcn_mfma_f32_32x32x16_bf16(        \
                    __builtin_bit_cast(bf16x8, ASET[ks]),                      \
                    __builtin_bit_cast(bf16x8, Bf[ks][nb]),                    \
                    acc[mb_][nb], 0, 0, 0);                                    \
        __builtin_amdgcn_s_setprio(0); } while (0)

#define BARR() __builtin_amdgcn_s_barrier()
#define SGB()  __builtin_amdgcn_sched_barrier(0)

    const int NT = K_IN / 64;   // 64 K-steps
    const int NI = NT / 2;      // 32 iterations

    // Prologue: s0 all 8 units; s1 first 6 (B x4, A q0,q1,q2... keep order:
    // B first then A so gate tail = Aq3 + Bp11? — use: Bx3 + Aq0..q2? No:
    // derived cadence tail at gate = STG_A(1,3,s1)+STG_B(1,1,1,s1)).
    STG_A(0, 0, 0); STG_A(0, 1, 0); STG_A(0, 2, 0); STG_A(0, 3, 0);
    STG_B(0, 0, 0, 0); STG_B(0, 0, 1, 0); STG_B(0, 1, 0, 0); STG_B(0, 1, 1, 0);
    STG_A(1, 0, 1); STG_A(1, 1, 1); STG_A(1, 2, 1);
    STG_B(1, 0, 0, 1); STG_B(1, 0, 1, 1); STG_B(1, 1, 0, 1);

    // gate0 (par0): s0 resident when only s1's 6 remain outstanding.
    asm volatile("s_waitcnt vmcnt(6)" ::: "memory");
    BARR(); SGB();
    RD_B(0); RD_A(AX, 0, 0);
    STG_A(1, 3, 1); STG_B(1, 1, 1, 1);
    BARR();

    for (int i = 0; i < NI; ++i) {
        const int s2 = 2 * i + 2, s3 = 2 * i + 3;
        const bool t2 = s2 < NT, t3 = s3 < NT;

        // ph1: read A q1; stage Aq0+Bp00 (s2); MFMA mb0
        RD_A(AY, 0, 1);
        if (t2) { STG_A(0, 0, s2); STG_B(0, 0, 0, s2); }
        BARR();
        MF(0, AX);
        // ph2
        RD_A(AX, 0, 2);
        if (t2) { STG_A(0, 1, s2); STG_B(0, 0, 1, s2); }
        BARR();
        MF(1, AY);
        // ph3
        RD_A(AY, 0, 3);
        if (t2) { STG_A(0, 2, s2); STG_B(0, 1, 0, s2); }
        BARR();
        MF(2, AX);
        // ph4 (gate par1): MFMA mb3 of par0 FIRST (frees Bf), then reload
        if (i < NI - 1) asm volatile("s_waitcnt vmcnt(6)" ::: "memory");
        else            asm volatile("s_waitcnt vmcnt(0)" ::: "memory");
        BARR(); SGB();
        MF(3, AY);
        RD_B(1); RD_A(AX, 1, 0);
        if (t2) { STG_A(0, 3, s2); STG_B(0, 1, 1, s2); }
        BARR();
        // ph5
        RD_A(AY, 1, 1);
        if (t3) { STG_A(1, 0, s3); STG_B(1, 0, 0, s3); }
        BARR();
        MF(0, AX);
        // ph6
        RD_A(AX, 1, 2);
        if (t3) { STG_A(1, 1, s3); STG_B(1, 0, 1, s3); }
        BARR();
        MF(1, AY);
        // ph7
        RD_A(AY, 1, 3);
        if (t3) { STG_A(1, 2, s3); STG_B(1, 1, 0, s3); }
        BARR();
        MF(2, AX);
        // ph0' (primes next iter): gate par0; MFMA mb3 of par1; reads; tail
        if (i < NI - 1) {
            asm volatile("s_waitcnt vmcnt(6)" ::: "memory");
            BARR(); SGB();
            MF(3, AY);
            RD_B(0); RD_A(AX, 0, 0);
            STG_A(1, 3, s3); STG_B(1, 1, 1, s3);
            BARR();
        }
    }
    // final: mb3 of the last par1 K-step
    MF(3, AY);
#undef STG_A
#undef STG_B
#undef RD_A
#undef RD_B
#undef MF
#undef BARR
#undef SGB

    // Epilogue: 32x32 C/D layout (m101): col = lane&31,
    // row = (reg&3) + 8*(reg>>2) + 4*(lane>>5)
#pragma unroll
    for (int nb = 0; nb < 2; ++nb) {
        const int ng = n_base + colc + wn * 64 + nb * 32 + ln31;
        const float bv = bias[ng];
#pragma unroll
        for (int mb = 0; mb < 4; ++mb) {
            f32x16 v = acc[mb][nb];
#pragma unroll
            for (int r = 0; r < 16; r++) {
                const int rowin = (r & 3) + 8 * (r >> 2) + 4 * kh;
                const size_t grow = blockM + wm * 128 + mb * 32 + rowin;
                C[grow * N_OUT + ng] = v[r] + bv;
            }
        }
    }
}

// ---------------------------------------------------------------------------
// Fallback: fully fused kernel (passed round 4, verbatim).
// ---------------------------------------------------------------------------
__global__ __launch_bounds__(256) void fused_w4a16_kernel(
    const float*        __restrict__ A,
    const unsigned int* __restrict__ qw,
    const unsigned int* __restrict__ qz,
    const float*        __restrict__ sc,
    const float*        __restrict__ bias,
    float*              __restrict__ C)
{
    __shared__ __align__(16) unsigned short As[128 * 64];
    __shared__ __align__(16) unsigned short Bs[128 * 64];

    const int tid = threadIdx.x;
    const int l   = tid & 63;
    const int w   = tid >> 6;
    const int wm  = w >> 1;
    const int wn  = w & 1;
    const size_t blockM = (size_t)blockIdx.x * 128;
    const int    colN   = blockIdx.y * 128;

    const float* Ag = A + blockM * K_IN;

    const int r_in = l >> 3;
    const int cch  = l & 7;
    int    aw_off[4];
    size_t ag_off[4];
#pragma unroll
    for (int qq = 0; qq < 4; qq++) {
        const int row = w * 32 + qq * 8 + r_in;
        aw_off[qq] = row * 64 + ((cch ^ r_in) * 8);
        ag_off[qq] = (size_t)row * K_IN + cch * 8;
    }

    const int kc = tid & 7;
    int ngl[4], j8[4], shn[4], bs_off[4];
#pragma unroll
    for (int p = 0; p < 4; p++) {
        const int nl = p * 32 + (tid >> 3);
        const int ng = colN + nl;
        ngl[p]    = ng;
        j8[p]     = ng >> 3;
        shn[p]    = 4 * (ng & 7);
        bs_off[p] = nl * 64 + ((kc ^ (nl & 7)) * 8);
    }

    f32x4 acc[4][4];
#pragma unroll
    for (int i = 0; i < 4; i++)
#pragma unroll
        for (int j = 0; j < 4; j++) acc[i][j] = (f32x4){0.f, 0.f, 0.f, 0.f};

    const int lrow = l & 15;
    const int lk   = l >> 4;
    const int NT   = K_IN / 64;

    for (int kt = 0; kt < NT; ++kt) {
        const int K0 = kt * 64;
        const int g  = K0 >> 7;

        float4 fa[4][2];
#pragma unroll
        for (int qq = 0; qq < 4; qq++) {
            fa[qq][0] = *(const float4*)(Ag + ag_off[qq] + K0);
            fa[qq][1] = *(const float4*)(Ag + ag_off[qq] + K0 + 4);
        }

        unsigned int q[4][8];
        float sf[4], nzs[4];
#pragma unroll
        for (int p = 0; p < 4; p++) {
            const unsigned int* qp = qw + (size_t)(K0 + kc * 8) * NP8 + j8[p];
#pragma unroll
            for (int i = 0; i < 8; i++) q[p][i] = qp[(size_t)i * NP8];
            const float zf = (float)((qz[(size_t)g * NP8 + j8[p]] >> shn[p]) & 0xFu);
            sf[p]  = sc[(size_t)g * N_OUT + ngl[p]];
            nzs[p] = -zf * sf[p];
        }

        __syncthreads();

#pragma unroll
        for (int qq = 0; qq < 4; qq++) {
            bf16x8 h;
#pragma unroll
            for (int i = 0; i < 4; i++) {
                h[i]     = (__bf16)(((const float*)&fa[qq][0])[i]);
                h[i + 4] = (__bf16)(((const float*)&fa[qq][1])[i]);
            }
            *(int4*)&As[aw_off[qq]] = __builtin_bit_cast(int4, h);
        }
#pragma unroll
        for (int p = 0; p < 4; p++) {
            bf16x8 h;
#pragma unroll
            for (int i = 0; i < 8; i++) {
                const float nib = (float)((q[p][i] >> shn[p]) & 0xFu);
                h[i] = (__bf16)fmaf(nib, sf[p], nzs[p]);
            }
            *(int4*)&Bs[bs_off[p]] = __builtin_bit_cast(int4, h);
        }

        __syncthreads();

#pragma unroll
        for (int ks = 0; ks < 2; ++ks) {
            s16x8 a[4], b[4];
            const int kcc = ks * 4 + lk;
#pragma unroll
            for (int mi = 0; mi < 4; mi++) {
                const int row = wm * 64 + mi * 16 + lrow;
                a[mi] = *(const s16x8*)&As[row * 64 + ((kcc ^ (row & 7)) * 8)];
            }
#pragma unroll
            for (int ni = 0; ni < 4; ni++) {
                const int row = wn * 64 + ni * 16 + lrow;
                b[ni] = *(const s16x8*)&Bs[row * 64 + ((kcc ^ (row & 7)) * 8)];
            }
#pragma unroll
            for (int mi = 0; mi < 4; mi++)
#pragma unroll
                for (int ni = 0; ni < 4; ni++)
                    acc[mi][ni] = __builtin_amdgcn_mfma_f32_16x16x32_bf16(
                        __builtin_bit_cast(bf16x8, a[mi]),
                        __builtin_bit_cast(bf16x8, b[ni]),
                        acc[mi][ni], 0, 0, 0);
        }
    }

#pragma unroll
    for (int ni = 0; ni < 4; ++ni) {
        const int ng = colN + wn * 64 + ni * 16 + lrow;
        const float bv = bias[ng];
#pragma unroll
        for (int mi = 0; mi < 4; ++mi) {
            f32x4 v = acc[mi][ni];
#pragma unroll
            for (int r = 0; r < 4; r++) {
                const size_t grow = blockM + wm * 64 + mi * 16 + lk * 4 + r;
                C[grow * N_OUT + ng] = v[r] + bv;
            }
        }
    }
}

// ---------------------------------------------------------------------------
extern "C" void kernel_launch(void* const* d_in, const int* in_sizes, int n_in,
                              void* d_out, int out_size, void* d_ws, size_t ws_size,
                              hipStream_t stream)
{
    const float*        x    = (const float*)d_in[0];
    const unsigned int* qw   = (const unsigned int*)d_in[1];
    const unsigned int* qz   = (const unsigned int*)d_in[2];
    const float*        sc   = (const float*)d_in[3];
    const float*        bias = (const float*)d_in[4];
    float*              out  = (float*)d_out;

    const size_t XBF    = (size_t)M_TOK * K_IN * 2;   // 64 MiB bf16 x
    const size_t COL256 = (size_t)256 * K_IN * 2;     // 2 MiB per 256 cols W^T

    if (ws_size >= XBF + COL256) {
        unsigned short* xb = (unsigned short*)d_ws;
        unsigned short* wt = (unsigned short*)((char*)d_ws + XBF);
        const long n8 = (long)M_TOK * K_IN / 8;
        convert_x_kernel<<<2048, 256, 0, stream>>>(x, xb, n8);

        size_t chunk_cols = ((ws_size - XBF) / COL256) * 256;
        if (chunk_cols > (size_t)N_OUT) chunk_cols = N_OUT;
        for (int n0 = 0; n0 < N_OUT; n0 += (int)chunk_cols) {
            int nc = N_OUT - n0;
            if (nc > (int)chunk_cols) nc = (int)chunk_cols;
            dequant_kernel<<<dim3(K_IN / GS, nc / 128), 256, 0, stream>>>(qw, qz, sc, wt, n0);
            gemm_8pw_kernel<<<32 * (nc / 256), 512, 0, stream>>>(xb, wt, bias, out, n0);
        }
    } else {
        fused_w4a16_kernel<<<dim3(M_TOK / 128, N_OUT / 128), 256, 0, stream>>>(
            x, qw, qz, sc, bias, out);
    }
}